// Round 6
// baseline (11.649 us; speedup 1.0000x reference)
//
#include <hip/hip_runtime.h>

// RoiPooling: img [B,32,32,256] f32, rois [B,64,4] f32 (x,y,w,h)
// Out [B*R, 21, 256]; bin order: 0 = level1, 1..4 = level2 (i*2+j),
// 5..20 = level4 (ix*4+jy).
// Level-1/2 boundaries bit-match even level-4 boundaries (k*(h/4) pow2-exact),
// so only the 4x4 level-4 grid is pooled from pixels; coarser levels reduce it.
// jnp.round == round-half-to-even == __float2int_rn.
//
// R5 -> R6: bounds are wave-uniform (wave = one bin of one ROI; only the
// channel quad varies per lane). readfirstlane -> SGPR bounds -> scalar
// branches + saddr loads; load exactly rw x cw (in [2,5]^2, avg ~12) float4s
// instead of a fixed 25 -> ~2x less L1 traffic, less address VALU, loads stay
// independent (s_cbranch doesn't block the memory pipe).
// Span >= 2 guaranteed: h >= 8 -> h/4 >= 2 -> round(a+d) >= round(a)+2.

#define IMG_H 32
#define IMG_W 32
#define NCH   256

static __device__ __forceinline__ float4 fmax4(float4 a, float4 b) {
    return make_float4(fmaxf(a.x, b.x), fmaxf(a.y, b.y),
                       fmaxf(a.z, b.z), fmaxf(a.w, b.w));
}

__global__ __launch_bounds__(1024) void roi_pool_kernel(
    const float* __restrict__ img,   // [B, H, W, C]
    const float* __restrict__ rois,  // [B*R, 4]
    float* __restrict__ out)         // [B*R, 21, C]
{
    const int br  = blockIdx.x;       // b*R + r
    const int b   = br >> 6;          // R = 64
    const int tid = threadIdx.x;
    const int c4  = tid & 63;         // float4 channel group: channels 4*c4..4*c4+3
    const int ix  = (tid >> 6) & 3;   // column bin
    const int jy  = tid >> 8;         // row bin

    const float4 roi = *reinterpret_cast<const float4*>(rois + (size_t)br * 4);
    const float x = roi.x, y = roi.y, w = roi.z, h = roi.w;

    // Column bins from (x, h); row bins from (y, w) — axis swap per reference.
    const float hq = h * 0.25f;   // exact h/4
    const float wq = w * 0.25f;
    // Wave-uniform -> force to SGPRs.
    const int c0 = __builtin_amdgcn_readfirstlane(
        max(__float2int_rn(x + (float)ix * hq), 0));
    const int c1 = __builtin_amdgcn_readfirstlane(
        min(__float2int_rn(x + (float)(ix + 1) * hq), IMG_W));
    const int r0 = __builtin_amdgcn_readfirstlane(
        max(__float2int_rn(y + (float)jy * wq), 0));
    const int r1 = __builtin_amdgcn_readfirstlane(
        min(__float2int_rn(y + (float)(jy + 1) * wq), IMG_H));
    const int cw = c1 - c0;   // 2..5, wave-uniform
    const int rw = r1 - r0;   // 2..5, wave-uniform

    const float* base = img
        + ((size_t)(b * IMG_H + r0) * IMG_W + c0) * NCH + (size_t)c4 * 4;

    const float NEG = -__builtin_inff();
    float4 m = make_float4(NEG, NEG, NEG, NEG);
#pragma unroll
    for (int j = 0; j < 5; ++j) {
        if (j < rw) {                       // scalar branch (uniform)
            const float* rp = base + (size_t)j * (IMG_W * NCH);
            // span >= 2: first two loads unconditional
            float4 a = fmax4(*reinterpret_cast<const float4*>(rp),
                             *reinterpret_cast<const float4*>(rp + NCH));
            if (cw > 2) a = fmax4(a, *reinterpret_cast<const float4*>(rp + 2 * NCH));
            if (cw > 3) a = fmax4(a, *reinterpret_cast<const float4*>(rp + 3 * NCH));
            if (cw > 4) a = fmax4(a, *reinterpret_cast<const float4*>(rp + 4 * NCH));
            m = fmax4(m, a);
        }
    }

    float* ob = out + (size_t)br * 21 * NCH;

    // level 4: bin 5 + ix*4 + jy
    *reinterpret_cast<float4*>(ob + (size_t)(5 + ix * 4 + jy) * NCH + (size_t)c4 * 4) = m;

    // share the 4x4 grid for level-2 / level-1 reduction
    __shared__ float4 P[4][4][64];   // [ix][jy][c4], 16 KB
    P[ix][jy][c4] = m;
    __syncthreads();

    if (tid < 256) {
        // level 2: 4 bins x 64 c4-groups. bin (i,j) = max of level4 (2i..2i+1, 2j..2j+1)
        const int cc = tid & 63;
        const int bb = tid >> 6;      // 0..3
        const int i  = bb >> 1, j = bb & 1;
        const float4 q = fmax4(
            fmax4(P[2 * i][2 * j][cc],     P[2 * i][2 * j + 1][cc]),
            fmax4(P[2 * i + 1][2 * j][cc], P[2 * i + 1][2 * j + 1][cc]));
        *reinterpret_cast<float4*>(ob + (size_t)(1 + i * 2 + j) * NCH + (size_t)cc * 4) = q;
    } else if (tid < 320) {
        // level 1: max over all 16 level-4 bins
        const int cc = tid & 63;
        float4 q = P[0][0][cc];
#pragma unroll
        for (int i = 0; i < 4; ++i)
#pragma unroll
            for (int j = 0; j < 4; ++j)
                if (i | j) q = fmax4(q, P[i][j][cc]);
        *reinterpret_cast<float4*>(ob + (size_t)cc * 4) = q;
    }
}

extern "C" void kernel_launch(void* const* d_in, const int* in_sizes, int n_in,
                              void* d_out, int out_size, void* d_ws, size_t ws_size,
                              hipStream_t stream) {
    const float* img  = (const float*)d_in[0];
    const float* rois = (const float*)d_in[1];
    float* out = (float*)d_out;

    const int n_rois = in_sizes[1] / 4;   // B * R = 256
    roi_pool_kernel<<<n_rois, 1024, 0, stream>>>(img, rois, out);
}

// Round 7
// 10.273 us; speedup vs baseline: 1.1339x; 1.1339x over previous
//
#include <hip/hip_runtime.h>

// RoiPooling: img [B,32,32,256] f32, rois [B,64,4] f32 (x,y,w,h)
// Out [B*R, 21, 256]; bin order: 0 = level1, 1..4 = level2 (i*2+j),
// 5..20 = level4 (ix*4+jy).
// Level-1/2 boundaries bit-match even level-4 boundaries (k*(h/4) pow2-exact),
// so only the 4x4 level-4 grid is pooled from pixels; coarser levels reduce it.
// jnp.round == round-half-to-even == __float2int_rn.
//
// R6 post-mortem: branchy exact-count loads REGRESSED (branches serialize the
// load stream). R7 = R5's 25 unconditional independent clamped loads, plus:
//  - readfirstlane'd wave-uniform bounds -> all clamp/address math on SALU,
//    loads in saddr+voffset form (voffset = c4*16, one v_add per pixel max)
//  - max3 reduction tree (nested fmaxf fuses to v_max3_f32): 96 -> ~48 ops
// Clamped duplicate loads stay inside the bin (every bin spans >= 2 px), so
// the unmasked max is bit-exact (see R5).

#define IMG_H 32
#define IMG_W 32
#define NCH   256
#define SPAN  5

static __device__ __forceinline__ float4 fmax4(float4 a, float4 b) {
    return make_float4(fmaxf(a.x, b.x), fmaxf(a.y, b.y),
                       fmaxf(a.z, b.z), fmaxf(a.w, b.w));
}
static __device__ __forceinline__ float4 fmax34(float4 a, float4 b, float4 c) {
    // nested fmaxf -> v_max3_f32
    return make_float4(fmaxf(fmaxf(a.x, b.x), c.x), fmaxf(fmaxf(a.y, b.y), c.y),
                       fmaxf(fmaxf(a.z, b.z), c.z), fmaxf(fmaxf(a.w, b.w), c.w));
}

__global__ __launch_bounds__(1024) void roi_pool_kernel(
    const float* __restrict__ img,   // [B, H, W, C]
    const float* __restrict__ rois,  // [B*R, 4]
    float* __restrict__ out)         // [B*R, 21, C]
{
    const int br  = blockIdx.x;       // b*R + r
    const int b   = br >> 6;          // R = 64
    const int tid = threadIdx.x;
    const int c4  = tid & 63;         // float4 channel group: channels 4*c4..4*c4+3
    const int ix  = (tid >> 6) & 3;   // column bin (wave-uniform)
    const int jy  = tid >> 8;         // row bin    (wave-uniform)

    const float4 roi = *reinterpret_cast<const float4*>(rois + (size_t)br * 4);
    const float x = roi.x, y = roi.y, w = roi.z, h = roi.w;

    // Column bins from (x, h); row bins from (y, w) — axis swap per reference.
    const float hq = h * 0.25f;   // exact h/4
    const float wq = w * 0.25f;
    // Wave-uniform bounds -> SGPRs; ALL following index math is scalar.
    const int c0 = __builtin_amdgcn_readfirstlane(
        max(__float2int_rn(x + (float)ix * hq), 0));
    const int c1 = __builtin_amdgcn_readfirstlane(
        min(__float2int_rn(x + (float)(ix + 1) * hq), IMG_W));
    const int r0 = __builtin_amdgcn_readfirstlane(
        max(__float2int_rn(y + (float)jy * wq), 0));
    const int r1 = __builtin_amdgcn_readfirstlane(
        min(__float2int_rn(y + (float)(jy + 1) * wq), IMG_H));

    // Clamped scalar indices (duplicates stay inside the bin).
    int rj[SPAN], ck[SPAN];
#pragma unroll
    for (int j = 0; j < SPAN; ++j) rj[j] = min(r0 + j, r1 - 1);
#pragma unroll
    for (int k = 0; k < SPAN; ++k) ck[k] = min(c0 + k, c1 - 1);

    const float* crop = img + (size_t)b * (IMG_H * IMG_W * NCH);  // uniform
    const int lane_off = c4 * 4;                                   // per-lane

    // 25 unconditional independent loads (saddr + voffset form).
    float4 v[SPAN * SPAN];
#pragma unroll
    for (int j = 0; j < SPAN; ++j) {
        const int rowoff = rj[j] * (IMG_W * NCH);                  // scalar
#pragma unroll
        for (int k = 0; k < SPAN; ++k) {
            v[j * SPAN + k] = *reinterpret_cast<const float4*>(
                crop + (size_t)(rowoff + ck[k] * NCH) + lane_off);
        }
    }

    // max3 tree over 25 values: 8 + 3 + 1 = 12 fmax34 per component-quad.
    float4 t0 = fmax34(v[0],  v[1],  v[2]);
    float4 t1 = fmax34(v[3],  v[4],  v[5]);
    float4 t2 = fmax34(v[6],  v[7],  v[8]);
    float4 t3 = fmax34(v[9],  v[10], v[11]);
    float4 t4 = fmax34(v[12], v[13], v[14]);
    float4 t5 = fmax34(v[15], v[16], v[17]);
    float4 t6 = fmax34(v[18], v[19], v[20]);
    float4 t7 = fmax34(v[21], v[22], v[23]);
    float4 u0 = fmax34(t0, t1, t2);
    float4 u1 = fmax34(t3, t4, t5);
    float4 u2 = fmax34(t6, t7, v[24]);
    const float4 m = fmax34(u0, u1, u2);

    float* ob = out + (size_t)br * 21 * NCH;

    // level 4: bin 5 + ix*4 + jy
    *reinterpret_cast<float4*>(ob + (size_t)(5 + ix * 4 + jy) * NCH + (size_t)lane_off) = m;

    // share the 4x4 grid for level-2 / level-1 reduction
    __shared__ float4 P[4][4][64];   // [ix][jy][c4], 16 KB
    P[ix][jy][c4] = m;
    __syncthreads();

    if (tid < 256) {
        // level 2: 4 bins x 64 c4-groups. bin (i,j) = max of level4 (2i..2i+1, 2j..2j+1)
        const int cc = tid & 63;
        const int bb = tid >> 6;      // 0..3
        const int i  = bb >> 1, j = bb & 1;
        const float4 q = fmax4(
            fmax4(P[2 * i][2 * j][cc],     P[2 * i][2 * j + 1][cc]),
            fmax4(P[2 * i + 1][2 * j][cc], P[2 * i + 1][2 * j + 1][cc]));
        *reinterpret_cast<float4*>(ob + (size_t)(1 + i * 2 + j) * NCH + (size_t)cc * 4) = q;
    } else if (tid < 320) {
        // level 1: max over all 16 level-4 bins
        const int cc = tid & 63;
        float4 q = fmax34(fmax34(P[0][0][cc], P[0][1][cc], P[0][2][cc]),
                          fmax34(P[0][3][cc], P[1][0][cc], P[1][1][cc]),
                          fmax34(P[1][2][cc], P[1][3][cc], P[2][0][cc]));
        q = fmax34(q,
                   fmax34(P[2][1][cc], P[2][2][cc], P[2][3][cc]),
                   fmax34(P[3][0][cc], P[3][1][cc], P[3][2][cc]));
        q = fmax4(q, P[3][3][cc]);
        *reinterpret_cast<float4*>(ob + (size_t)cc * 4) = q;
    }
}

extern "C" void kernel_launch(void* const* d_in, const int* in_sizes, int n_in,
                              void* d_out, int out_size, void* d_ws, size_t ws_size,
                              hipStream_t stream) {
    const float* img  = (const float*)d_in[0];
    const float* rois = (const float*)d_in[1];
    float* out = (float*)d_out;

    const int n_rois = in_sizes[1] / 4;   // B * R = 256
    roi_pool_kernel<<<n_rois, 1024, 0, stream>>>(img, rois, out);
}